// Round 11
// baseline (257.598 us; speedup 1.0000x reference)
//
#include <hip/hip_runtime.h>

// RoI2Det, R22. R21 (reg/readlane scan) gave the first real win: 109.6->104.3.
// R20's counters pin the mechanism: hot-cache nms = 44us @ VALUBusy 40% =>
// core clock ~500MHz during micro-kernels (DVFS parked by the HBM-bound
// poison fills). At ~500MHz the block-critical path is SERIAL INSTRUCTION
// COUNT (memory latency in cycles is cheap). R22 cuts instructions:
//  1. T_A computed in cand via last-block-done (atomic gdone[b]; 125th
//     block's wave 0 suffix-scans ghist -> gthr[b]) — nms loses its ghist
//     round + Phase B entirely.
//  2. TARGET 128 / CAPA 192 (rank_100 ~110; nkept<100 guard keeps exactness):
//     sort <=96 iters, rows 3 u64 words.
//  3. IoU bit-matrix in 64x32 subtiles (<=12 over 16 waves): inner loop 32
//     iters instead of 64 on the barrier-critical wave.
//  4. Keys register-staged at nms entry (all loads in flight during the
//     gthr/gcur round); filter is pure ALU.
//
// Exactness: mode A sorts the exact top-S (S in [TARGET,CAPA]) selected by
// the monotone fine histogram (T_A semantics identical, computed from the
// completed ghist under a release/acquire done-counter). Guards (M>CAPIMG,
// S_A>CAPA, nkept<100 with uncovered candidates) route to nmsB (exact).
//
// ws: [0,16) u32 gcur[4]; [16,32) u32 gdone[4]; [64,37952) u32 ghist[4][2368]
//     (all memset); [37952,37968) int gflag[4]; [37968,38032) int gthr[4][4];
//     [38080,300224) u64 gkeys[4][8192]; [300224,824512) float4 gbox[4][8192].
// key = (score_bits<<32) | (0xFFFFFFFF - flat_idx): desc order == lax.top_k.

typedef unsigned long long u64;
typedef unsigned int u32;

#define B_ 4
#define N_ 2000
#define C_ 80
#define NCLS 81
#define KPRE 2000
#define MAXDET 100
#define TARGET 128      // mode-A prefix floor (rank_100 ~ 110 observed)
#define NB 2312         // fine score buckets
#define NBPAD 2368      // 37*64
#define NG 37
#define HBASE 0xF500
#define KSHIFT 46       // key>>46 == score_bits>>14
#define CAPA 192
#define CAPB 2048
#define CAPIMG 8192     // per-image contiguous key cap (expected M ~ 4500)
#define KPT 8           // staged key rounds (8*1024 = CAPIMG)
#define BPI 125         // producer blocks per image
#define BIGI 0x7fffffff
#define MAXR 4.135166556742356f  // |log(16/1000)|

// ws offsets
#define WS_GCUR  0       // memset
#define WS_GDONE 16      // memset
#define WS_GHIST 64      // memset ends 37952
#define WS_GFLAG 37952
#define WS_GTHR  37968
#define WS_GKEYS 38080   // ends 300224
#define WS_GBOX  300224  // ends 824512
#define WS_ZEND  37952   // memset [0, WS_ZEND)

__device__ __forceinline__ u64 pack_key(float score, unsigned fi) {
  return ((u64)__float_as_uint(score) << 32) | (u64)(0xFFFFFFFFu - fi);
}
__device__ __forceinline__ int bucket_of_bits(u32 sb) {
  return min(max((int)(sb >> 14) - HBASE, 0), NB - 1);
}
__device__ __forceinline__ u64 rdlane64(u64 v, int l) {
  u32 lo = (u32)__builtin_amdgcn_readlane((int)(u32)v, l);
  u32 hi = (u32)__builtin_amdgcn_readlane((int)(v >> 32), l);
  return ((u64)hi << 32) | lo;
}

// ---- wave64 reductions via DPP (VALU-only) ----
__device__ __forceinline__ float wred_max(float v) {
  int t;
#define STEPM(ctrl)                                                          \
  t = __builtin_amdgcn_update_dpp(__float_as_int(v), __float_as_int(v),      \
                                  (ctrl), 0xF, 0xF, false);                  \
  v = fmaxf(v, __int_as_float(t));
  STEPM(0x111) STEPM(0x112) STEPM(0x114) STEPM(0x118) STEPM(0x142) STEPM(0x143)
#undef STEPM
  return __int_as_float(__builtin_amdgcn_readlane(__float_as_int(v), 63));
}
__device__ __forceinline__ float wred_sum(float v) {
  int t;
#define STEPS(ctrl)                                                          \
  t = __builtin_amdgcn_update_dpp(0, __float_as_int(v), (ctrl), 0xF, 0xF,    \
                                  false);                                    \
  v = v + __int_as_float(t);
  STEPS(0x111) STEPS(0x112) STEPS(0x114) STEPS(0x118) STEPS(0x142) STEPS(0x143)
#undef STEPS
  return __int_as_float(__builtin_amdgcn_readlane(__float_as_int(v), 63));
}

// decode_one: used ONLY by nmsB (cold, never fetched when flag==0).
__device__ __forceinline__ float4 decode_one(
    u64 kk, const float* __restrict__ reg, const float* __restrict__ props,
    int b, float h, float w, float offscale) {
  unsigned fi = 0xFFFFFFFFu - (u32)kk;
  int n = (int)(fi / (unsigned)C_);
  int c = (int)(fi - (unsigned)n * (unsigned)C_);
  float4 p = ((const float4*)props)[b * N_ + n];
  const float* dl = reg + ((size_t)(b * N_ + n)) * (C_ * 4) + c * 4;
  float dx = dl[0] * 0.1f;
  float dy = dl[1] * 0.1f;
  float dw = fminf(fmaxf(dl[2] * 0.2f, -MAXR), MAXR);
  float dh = fminf(fmaxf(dl[3] * 0.2f, -MAXR), MAXR);
  float px = (p.x + p.z) * 0.5f, py = (p.y + p.w) * 0.5f;
  float pw = p.z - p.x, ph = p.w - p.y;
  float gx = px + pw * dx, gy = py + ph * dy;
  float gw = pw * expf(dw), gh = ph * expf(dh);
  float off = (float)c * offscale;  // cross-class IoU exactly 0 after offset
  return make_float4(fminf(fmaxf(gx - gw * 0.5f, 0.0f), w) + off,
                     fminf(fmaxf(gy - gh * 0.5f, 0.0f), h) + off,
                     fminf(fmaxf(gx + gw * 0.5f, 0.0f), w) + off,
                     fminf(fmaxf(gy + gh * 0.5f, 0.0f), h) + off);
}

// -- producer: softmax -> keys + decoded boxes + hist; LAST block computes
//    T_A/S_A/Mtot for its image from the completed histogram -> gthr[b]. --
__global__ __launch_bounds__(1024) void cand_kernel(
    const float* __restrict__ cls, const float* __restrict__ reg,
    const float* __restrict__ props, const int* __restrict__ hw,
    u64* __restrict__ gkeys, float4* __restrict__ gbox,
    u32* __restrict__ gcur, u32* __restrict__ gdone,
    u32* __restrict__ ghist, int* __restrict__ gthr) {
  __shared__ int s_wc[16], s_woff[16];
  __shared__ int s_base;
  const int tid = threadIdx.x;
  const int wvi = tid >> 6, lane = tid & 63;
  const int blk = blockIdx.x;
  const int b = blk / BPI;
  const int n = (blk % BPI) * 16 + wvi;
  const float* lg = cls + (size_t)(b * N_ + n) * NCLS;
  float x0 = lg[lane];
  float x1 = (lane < 17) ? lg[64 + lane] : -3.0e38f;
  float mx = wred_max(fmaxf(x0, x1));
  float e0 = expf(x0 - mx);
  float e1 = (lane < 17) ? expf(x1 - mx) : 0.0f;
  float sum = wred_sum(e0 + e1);
  float sc0 = e0 / sum, sc1 = e1 / sum;
  bool p0 = sc0 > 0.05f;
  bool p1 = (lane < 16) && (sc1 > 0.05f);  // class 80 = background
  u64 m0 = __ballot(p0), m1 = __ballot(p1);
  int c0 = __popcll(m0);
  if (lane == 0) s_wc[wvi] = c0 + __popcll(m1);
  __syncthreads();
  if (tid == 0) {
    int acc = 0;
#pragma unroll
    for (int i = 0; i < 16; ++i) { s_woff[i] = acc; acc += s_wc[i]; }
    s_base = (acc > 0) ? (int)atomicAdd(&gcur[b], (u32)acc) : 0;
  }
  __syncthreads();
  const int base = s_base + s_woff[wvi];
  const u64 lt = (1ull << lane) - 1;
  u64* gk = gkeys + (size_t)b * CAPIMG;
  float4* gbx = gbox + (size_t)b * CAPIMG;
  u32* gh = ghist + (size_t)b * NBPAD;
  float hh = (float)hw[b * 2 + 0];
  float ww = (float)hw[b * 2 + 1];
  float offscale = fmaxf(hh, ww) + 1.0f;
  float4 p = ((const float4*)props)[b * N_ + n];
  float px = (p.x + p.z) * 0.5f, py = (p.y + p.w) * 0.5f;
  float pw = p.z - p.x, ph = p.w - p.y;
#pragma unroll 1
  for (int t = 0; t < 2; t++) {  // one code copy for both candidate slots
    bool pp = t ? p1 : p0;
    if (!pp) continue;
    float sc = t ? sc1 : sc0;
    int c = t ? (64 + lane) : lane;
    int slot = base + (t ? (c0 + __popcll(m1 & lt)) : __popcll(m0 & lt));
    atomicAdd(&gh[bucket_of_bits(__float_as_uint(sc))], 1u);
    if (slot < CAPIMG) {
      gk[slot] = pack_key(sc, (unsigned)(n * C_ + c));
      const float4 d4 =
          *(const float4*)(reg + ((size_t)(b * N_ + n)) * (C_ * 4) + c * 4);
      float dx = d4.x * 0.1f, dy = d4.y * 0.1f;
      float dw = fminf(fmaxf(d4.z * 0.2f, -MAXR), MAXR);
      float dh = fminf(fmaxf(d4.w * 0.2f, -MAXR), MAXR);
      float gx = px + pw * dx, gy = py + ph * dy;
      float gw = pw * expf(dw), gh2 = ph * expf(dh);
      float off = (float)c * offscale;
      gbx[slot] = make_float4(fminf(fmaxf(gx - gw * 0.5f, 0.0f), ww) + off,
                              fminf(fmaxf(gy - gh2 * 0.5f, 0.0f), hh) + off,
                              fminf(fmaxf(gx + gw * 0.5f, 0.0f), ww) + off,
                              fminf(fmaxf(gy + gh2 * 0.5f, 0.0f), hh) + off);
    }
  }

  // ---- last-block-done: release this block's atomics, count arrivals;
  //      the 125th block's wave 0 computes T_A/S_A/Mtot -> gthr[b]. ----
  __threadfence();
  __syncthreads();
  if (tid < 64) {
    int done = 0;
    if (lane == 0)
      done = (int)__hip_atomic_fetch_add(&gdone[b], 1u, __ATOMIC_ACQ_REL,
                                         __HIP_MEMORY_SCOPE_AGENT);
    done = __shfl(done, 0);
    if (done == BPI - 1) {
      int acc = 0, T_A = 0, S_A = -1;
      for (int g = NG - 1; g >= 0; --g) {
        int v = (int)__hip_atomic_load(&gh[(g << 6) | lane], __ATOMIC_RELAXED,
                                       __HIP_MEMORY_SCOPE_AGENT);
        int gs = v;
#pragma unroll
        for (int o = 32; o; o >>= 1) gs += __shfl_xor(gs, o);
        if (S_A < 0 && acc + gs >= TARGET) {
          int fv = v;  // suffix over lanes: sum_{k>=lane} v_k
#pragma unroll
          for (int off = 1; off < 64; off <<= 1) {
            int src = lane + off;
            int o = __shfl(fv, src < 64 ? src : 63);
            if (src < 64) fv += o;
          }
          int cum = acc + fv;
          u64 pm2 = __ballot(cum >= TARGET);
          int tr = 63 - __builtin_clzll(pm2);
          T_A = (g << 6) + tr;
          S_A = __shfl(cum, tr);
        }
        acc += gs;
      }
      if (S_A < 0) { T_A = 0; S_A = acc; }
      if (lane == 0) {
        gthr[b * 4 + 0] = T_A;
        gthr[b * 4 + 1] = S_A;
        gthr[b * 4 + 2] = acc;  // Mtot
      }
    }
  }
}

// ---------------- nms: minimal-instruction consumer (4 blocks) --------------
// LDS (14416 B): U u64[194]@0; SS u64[192]@1552; rb u64[192*4]@3088;
// bxA float4[192]@9232; Upos u32[192]@12304; rankA i32[192]@13072;
// outl i32[128]@13840; misc i32[16]@14352.
// misc: 0=T_A 1=S_A 2=Mtot 4=cnt 5=M 6=nk 7=ovf. Writers: tid0->4;
// tid64->0,1,2; tid512->5,7; scan lane0->6. No overlaps.
__global__ __launch_bounds__(1024) void nms_kernel(
    const int* __restrict__ hw, const u64* __restrict__ gkeys,
    const float4* __restrict__ gbox, const u32* __restrict__ gcur,
    const int* __restrict__ gthr, int* __restrict__ gflag,
    float* __restrict__ out) {
  __shared__ u64 lds8[1802];  // 14416 B
  char* bp = (char*)lds8;
  u64* U = (u64*)bp;
  u64* SS = (u64*)(bp + 1552);
  u64* rb = (u64*)(bp + 3088);
  float4* bxA = (float4*)(bp + 9232);
  u32* Upos = (u32*)(bp + 12304);
  int* rankA = (int*)(bp + 13072);
  int* outl = (int*)(bp + 13840);
  int* misc = (int*)(bp + 14352);

  const int b = blockIdx.x, tid = threadIdx.x;
  const int wv = tid >> 6, lane = tid & 63;

  // ---- entry: stage ALL keys into regs (unguarded; in flight during the
  //      scalar gthr/gcur round below). ----
  const u64* keys = gkeys + (size_t)b * CAPIMG;
  u64 kreg[KPT];
#pragma unroll
  for (int r = 0; r < KPT; r++) kreg[r] = keys[tid + (r << 10)];

  if (tid == 0) misc[4] = 0;
  if (tid == 64) {  // wave 1: T_A/S_A/Mtot from gthr
    misc[0] = gthr[b * 4 + 0];
    misc[1] = gthr[b * 4 + 1];
    misc[2] = gthr[b * 4 + 2];
  }
  if (tid == 512) {  // wave 8: gcur
    u32 Mraw = gcur[b];
    misc[5] = min((int)Mraw, CAPIMG);
    misc[7] = (Mraw > (u32)CAPIMG) ? 1 : 0;
  }
  __syncthreads();

  const int T_A = misc[0], S_A = misc[1], Mtot = misc[2], M = misc[5];
  if (S_A > CAPA || misc[7] != 0) {
    if (tid == 0) gflag[b] = 1;  // nmsB handles this image
    return;
  }

  // ---- filter staged keys by T_A, ballot-compact into U/Upos (pure ALU). --
  {
    const u64 lt = (1ull << lane) - 1;
#pragma unroll 1
    for (int r = 0; r < KPT; r++) {
      int idx = tid + (r << 10);
      bool pr = (idx < M) && (bucket_of_bits((u32)(kreg[r] >> 32)) >= T_A);
      u64 mk = __ballot(pr);
      if (mk) {
        int wbase = 0;
        if (lane == 0) wbase = atomicAdd(&misc[4], __popcll(mk));
        wbase = __shfl(wbase, 0);
        if (pr) {
          int pos = wbase + __popcll(mk & lt);
          if (pos < CAPA) { U[pos] = kreg[r]; Upos[pos] = (u32)idx; }
        }
      }
    }
  }
  __syncthreads();
  int S = misc[4];
  if (S > CAPA) S = CAPA;
  if (tid == 0 && (S & 1)) U[S] = 0ULL;
  __syncthreads();

  // ---- rank-scatter sort (S<=192) + box gather. ----
  if (tid < S) {
    u64 k1 = U[tid];
    int r1 = 0;
    const ulonglong2* Uu2 = (const ulonglong2*)U;
    int half = (S + 1) >> 1;
    for (int k = 0; k < half; k++) {
      ulonglong2 kk = Uu2[k];
      r1 += (kk.x > k1) + (kk.y > k1);
    }
    rankA[tid] = r1;
  }
  __syncthreads();
  if (tid < S) {
    int r1 = rankA[tid];
    SS[r1] = U[tid];
    bxA[r1] = gbox[(size_t)b * CAPIMG + Upos[tid]];
  }
  __syncthreads();

  // ---- IoU bit-matrix in 64x32 subtiles (<=12 over 16 waves). ----
  int nwords = (S + 63) >> 6;   // <= 3
  int nh = (S + 31) >> 5;       // <= 6
  {
    int ti = 0, rem = wv;
    bool have = false;
    while (ti < nwords) {
      int cnt = nh - 2 * ti;
      if (cnt <= 0) break;
      if (rem < cnt) { have = true; break; }
      rem -= cnt;
      ti++;
    }
    if (have) {
      int tjh = 2 * ti + rem;
      int i = (ti << 6) + lane;
      float4 bi4 = bxA[i];
      float ai = (bi4.z - bi4.x) * (bi4.w - bi4.y);
      u32 bits = 0;
      int jbase = tjh << 5;
      int jcount = min(32, S - jbase);
      for (int jj = 0; jj < jcount; jj++) {
        int j = jbase + jj;
        float4 bj = bxA[j];
        float aj = (bj.z - bj.x) * (bj.w - bj.y);
        float iw = fmaxf(fminf(bi4.z, bj.z) - fmaxf(bi4.x, bj.x), 0.0f);
        float ih = fmaxf(fminf(bi4.w, bj.w) - fmaxf(bi4.y, bj.y), 0.0f);
        float inter = iw * ih;
        float iou = inter / (ai + aj - inter + 1e-6f);
        if (j > i && iou > 0.5f) bits |= (1u << jj);
      }
      if (i < S) ((u32*)rb)[i * 8 + tjh] = bits;
    }
  }
  __syncthreads();

  // ---- register/readlane greedy scan (wave 0), 3 chunks. ----
  if (tid < 64) {
    u64 R[3][3];
#pragma unroll
    for (int c2 = 0; c2 < 3; c2++) {
#pragma unroll
      for (int w2 = 0; w2 < 3; w2++) {
        R[c2][w2] = (w2 >= c2) ? rb[((c2 << 6) + lane) * 4 + w2] : 0ull;
      }
    }
    u64 al[3];
#pragma unroll
    for (int w2 = 0; w2 < 3; w2++) {
      int lo = w2 << 6;
      al[w2] = (S > lo) ? ((S - lo >= 64) ? ~0ull : ((1ull << (S - lo)) - 1))
                        : 0ull;
    }
    int nk = 0;
#pragma unroll
    for (int c2 = 0; c2 < 3; c2++) {
      u64 a = al[c2];
      while (a) {
        int i = __builtin_ctzll(a);  // uniform across the wave
        if (lane == 0) outl[nk] = (c2 << 6) + i;
        nk++;
        if (nk >= MAXDET) break;
        a &= a - 1;                      // drop bit i
        a &= ~rdlane64(R[c2][c2], i);    // in-chunk suppression
#pragma unroll
        for (int w2 = c2 + 1; w2 < 3; w2++)
          al[w2] &= ~rdlane64(R[c2][w2], i);  // cross-chunk suppression
      }
      if (nk >= MAXDET) break;
    }
    if (lane == 0) misc[6] = nk;
  }
  __syncthreads();
  const int nkept = misc[6];
  bool modeB = (nkept < MAXDET && S < Mtot && S < KPRE);
  if (tid == 0) gflag[b] = modeB ? 1 : 0;
  if (modeB) return;

  // Output: boxes [B,100,4] | scores [B,100] | labels [B,100].
  float h = (float)hw[b * 2 + 0];
  float w = (float)hw[b * 2 + 1];
  float offscale = fmaxf(h, w) + 1.0f;
  float* oBox = out;
  float* oSc = out + B_ * MAXDET * 4;
  float* oLb = out + B_ * MAXDET * 5;
  if (tid < MAXDET) {
    float4 bb = make_float4(0.0f, 0.0f, 0.0f, 0.0f);
    float sv = 0.0f, lv = -1.0f;
    if (tid < nkept) {
      int idx = outl[tid];
      u64 kk = SS[idx];
      sv = __uint_as_float((u32)(kk >> 32));
      unsigned fi = 0xFFFFFFFFu - (u32)kk;
      int c = (int)(fi % (unsigned)C_);
      float off = (float)c * offscale;
      float4 ob = bxA[idx];
      bb = make_float4(ob.x - off, ob.y - off, ob.z - off, ob.w - off);
      lv = (float)c;
    }
    oBox[(b * MAXDET + tid) * 4 + 0] = bb.x;
    oBox[(b * MAXDET + tid) * 4 + 1] = bb.y;
    oBox[(b * MAXDET + tid) * 4 + 2] = bb.z;
    oBox[(b * MAXDET + tid) * 4 + 3] = bb.w;
    oSc[b * MAXDET + tid] = sv;
    oLb[b * MAXDET + tid] = lv;
  }
}

// ---------------- nmsB: exact fallback (flag-gated, contiguous) -------------
__global__ __launch_bounds__(1024) void nmsB_kernel(
    const float* __restrict__ reg, const float* __restrict__ props,
    const int* __restrict__ hw, const u64* __restrict__ gkeys,
    const u32* __restrict__ gcur, const int* __restrict__ gflag,
    float* __restrict__ out) {
  const int b = blockIdx.x, tid = threadIdx.x;
  if (gflag[b] == 0) return;  // block-uniform fast exit (the normal case)

  __shared__ u64 lds8[7952];
  char* bp = (char*)lds8;
  u32* hist = (u32*)(bp + 0);          // [0,9472)
  u64* U2 = (u64*)(bp + 9472);         // 2048 keys
  u64* SSB = (u64*)(bp + 25856);       // 2048 sorted
  int* outl = (int*)(bp + 42240);      // 128
  int* misc = (int*)(bp + 42752);      // 16
  const int lane = tid & 63;

  float h = (float)hw[b * 2 + 0];
  float w = (float)hw[b * 2 + 1];
  float offscale = fmaxf(h, w) + 1.0f;

  const u64* keys = gkeys + (size_t)b * CAPIMG;
  const int M = min((int)gcur[b], CAPIMG);

  for (int i = tid; i < NBPAD; i += 1024) hist[i] = 0;
  if (tid < 16) misc[tid] = 0;
  __syncthreads();

  // Histogram from contiguous keys.
  for (int idx = tid; idx < M; idx += 1024) {
    u64 key = keys[idx];
    int bi = min(max((int)(key >> KSHIFT) - HBASE, 0), NB - 1);
    atomicAdd(&hist[bi], 1u);
  }
  __syncthreads();

  // T_B: serial suffix walk (cold path).
  if (tid == 0) {
    int acc = 0, tb = 0;
    for (int bi = NB - 1; bi >= 0; bi--) {
      acc += (int)hist[bi];
      if (acc >= KPRE) { tb = bi; break; }
    }
    if (acc > CAPB) tb = min(tb + 1, NB - 1);  // fat-bucket guard
    misc[1] = tb;
    misc[4] = 0;
  }
  __syncthreads();
  int T_B = misc[1];

  // Compact bucket >= T_B into U2 (ballot-aggregated).
  for (int idx0 = 0; idx0 < M; idx0 += 1024) {
    int idx = idx0 + tid;
    bool pred = false;
    u64 key = 0;
    if (idx < M) {
      key = keys[idx];
      int bi = min(max((int)(key >> KSHIFT) - HBASE, 0), NB - 1);
      pred = (bi >= T_B);
    }
    u64 mk = __ballot(pred);
    if (mk) {
      int wbase = 0;
      if (lane == 0) wbase = atomicAdd(&misc[4], __popcll(mk));
      wbase = __shfl(wbase, 0);
      if (pred) {
        int pos = wbase + __popcll(mk & ((1ull << lane) - 1));
        if (pos < CAPB) U2[pos] = key;
      }
    }
  }
  __syncthreads();
  int S = misc[4];
  if (S > CAPB) S = CAPB;
  {  // rank-scatter sort, 2 keys/thread
    int j1 = tid, j2 = tid + 1024;
    u64 k1 = (j1 < S) ? U2[j1] : 0ULL;
    u64 k2 = (j2 < S) ? U2[j2] : 0ULL;
    int r1 = 0, r2 = 0;
    for (int k = 0; k < S; k++) {
      u64 kk = U2[k];
      r1 += (kk > k1);
      r2 += (kk > k2);
    }
    __syncthreads();
    if (j1 < S) SSB[r1] = k1;
    if (j2 < S) SSB[r2] = k2;
  }
  __syncthreads();
  int K = (S < KPRE) ? S : KPRE;  // exact top-2000 (or all if fewer)
  // NMS with per-thread register boxes.
  int j1 = tid, j2 = tid + 1024;
  bool kp1 = (j1 < K), kp2 = (j2 < K);
  float4 bb1 = kp1 ? decode_one(SSB[j1], reg, props, b, h, w, offscale)
                   : make_float4(0, 0, 0, 0);
  float4 bb2 = kp2 ? decode_one(SSB[j2], reg, props, b, h, w, offscale)
                   : make_float4(0, 0, 0, 0);
  int nk = 0;
  if (K > 0) {
    int i = 0;
    for (;;) {
      if (tid == 0) { outl[nk] = i; misc[5] = K; }
      nk++;
      if (nk >= MAXDET) break;
      __syncthreads();
      float4 tb = decode_one(SSB[i], reg, props, b, h, w, offscale);
      float ai = (tb.z - tb.x) * (tb.w - tb.y);
      int ln = K;
      if (kp1 && j1 > i) {
        float aj = (bb1.z - bb1.x) * (bb1.w - bb1.y);
        float iw = fmaxf(fminf(tb.z, bb1.z) - fmaxf(tb.x, bb1.x), 0.0f);
        float ih = fmaxf(fminf(tb.w, bb1.w) - fmaxf(tb.y, bb1.y), 0.0f);
        float inter = iw * ih;
        float iou = inter / (ai + aj - inter + 1e-6f);
        if (iou > 0.5f) kp1 = false;
        else ln = min(ln, j1);
      }
      if (kp2 && j2 > i) {
        float aj = (bb2.z - bb2.x) * (bb2.w - bb2.y);
        float iw = fmaxf(fminf(tb.z, bb2.z) - fmaxf(tb.x, bb2.x), 0.0f);
        float ih = fmaxf(fminf(tb.w, bb2.w) - fmaxf(tb.y, bb2.y), 0.0f);
        float inter = iw * ih;
        float iou = inter / (ai + aj - inter + 1e-6f);
        if (iou > 0.5f) kp2 = false;
        else ln = min(ln, j2);
      }
#pragma unroll
      for (int off = 32; off; off >>= 1) ln = min(ln, __shfl_xor(ln, off));
      if ((tid & 63) == 0 && ln < K) atomicMin(&misc[5], ln);
      __syncthreads();
      int ni = misc[5];
      __syncthreads();
      if (ni >= K) break;
      i = ni;
    }
  }
  if (tid == 0) misc[6] = nk;
  __syncthreads();
  int nkept = misc[6];

  float* oBox = out;
  float* oSc = out + B_ * MAXDET * 4;
  float* oLb = out + B_ * MAXDET * 5;
  for (int k2 = tid; k2 < MAXDET; k2 += 1024) {
    float4 bb = make_float4(0.0f, 0.0f, 0.0f, 0.0f);
    float sv = 0.0f, lv = -1.0f;
    if (k2 < nkept) {
      int idx = outl[k2];
      u64 kk = SSB[idx];
      sv = __uint_as_float((u32)(kk >> 32));
      unsigned fi = 0xFFFFFFFFu - (u32)kk;
      int c = (int)(fi % (unsigned)C_);
      float off = (float)c * offscale;
      float4 ob = decode_one(kk, reg, props, b, h, w, offscale);
      bb = make_float4(ob.x - off, ob.y - off, ob.z - off, ob.w - off);
      lv = (float)c;
    }
    oBox[(b * MAXDET + k2) * 4 + 0] = bb.x;
    oBox[(b * MAXDET + k2) * 4 + 1] = bb.y;
    oBox[(b * MAXDET + k2) * 4 + 2] = bb.z;
    oBox[(b * MAXDET + k2) * 4 + 3] = bb.w;
    oSc[b * MAXDET + k2] = sv;
    oLb[b * MAXDET + k2] = lv;
  }
}

extern "C" void kernel_launch(void* const* d_in, const int* in_sizes, int n_in,
                              void* d_out, int out_size, void* d_ws, size_t ws_size,
                              hipStream_t stream) {
  const float* cls = (const float*)d_in[0];    // [B,N,81] f32
  const float* reg = (const float*)d_in[1];    // [B,N,320] f32
  const float* props = (const float*)d_in[2];  // [B,N,4] f32
  const int* hw = (const int*)d_in[3];         // [B,2] i32
  float* out = (float*)d_out;                  // 2400 f32

  u32* gcur = (u32*)((char*)d_ws + WS_GCUR);
  u32* gdone = (u32*)((char*)d_ws + WS_GDONE);
  u32* ghist = (u32*)((char*)d_ws + WS_GHIST);
  int* gflag = (int*)((char*)d_ws + WS_GFLAG);
  int* gthr = (int*)((char*)d_ws + WS_GTHR);
  u64* gkeys = (u64*)((char*)d_ws + WS_GKEYS);
  float4* gbox = (float4*)((char*)d_ws + WS_GBOX);

  hipMemsetAsync(d_ws, 0, WS_ZEND, stream);
  cand_kernel<<<B_ * BPI, 1024, 0, stream>>>(cls, reg, props, hw, gkeys, gbox,
                                             gcur, gdone, ghist, gthr);
  nms_kernel<<<B_, 1024, 0, stream>>>(hw, gkeys, gbox, gcur, gthr, gflag, out);
  nmsB_kernel<<<B_, 1024, 0, stream>>>(reg, props, hw, gkeys, gcur, gflag, out);
}

// Round 12
// 98.394 us; speedup vs baseline: 2.6180x; 2.6180x over previous
//
#include <hip/hip_runtime.h>

// RoI2Det, R23 = R21 (best known, 104.3us) + safe instruction cuts.
// R22 LESSON: last-block-done (per-block agent-scope __threadfence + ACQ_REL
// atomic across 500 blocks) stalled cand 6.5 -> 176us (VALUBusy 1.7% @ 62%
// occupancy = resident-but-fence-stalled). Cross-block fences on the wide
// path cost ~100x what they save. Reverted; T_A stays in nms.
//
// Mechanism (R20/R21): core clock ~500MHz during micro-kernels (DVFS parked
// by the HBM-bound poison fills) => block critical path ~ serial instruction
// count. Cuts applied here (none touch cross-block sync):
//  1. TARGET 128 / CAPA 192: sort <=96 iters, scan state 3 u64 words.
//  2. IoU bit-matrix in 64x32 subtiles (<=12 tiles / 16 waves): inner 32.
//  3. Keys register-staged at entry (latency hides under ghist round).
//  4. cand/nmsB byte-identical to R21 (passed, absmax 0).
//
// Exactness: mode A sorts the exact top-S (S in [TARGET,CAPA]) selected by
// the monotone fine histogram. Guards (M>CAPIMG, S_A>CAPA, nkept<100 with
// uncovered candidates) route to nmsB which redoes everything exactly.
//
// ws: [0,16) u32 gcur[4] (memset); [64,37952) u32 ghist[4][2368] (memset);
//     [37952,37968) int gflag[4]; [38016,300160) u64 gkeys[4][8192];
//     [300160,824448) float4 gbox[4][8192].
// key = (score_bits<<32) | (0xFFFFFFFF - flat_idx): desc order == lax.top_k.

typedef unsigned long long u64;
typedef unsigned int u32;

#define B_ 4
#define N_ 2000
#define C_ 80
#define NCLS 81
#define KPRE 2000
#define MAXDET 100
#define TARGET 128      // mode-A prefix floor (rank_100 ~ 110 observed)
#define NB 2312         // fine score buckets
#define NBPAD 2368      // 37*64
#define NG 37
#define HBASE 0xF500
#define KSHIFT 46       // key>>46 == score_bits>>14
#define CAPA 192
#define CAPB 2048
#define CAPIMG 8192     // per-image contiguous key cap (expected M ~ 4500)
#define KPT 8           // staged key rounds (8*1024 = CAPIMG)
#define BPI 125         // producer blocks per image
#define BIGI 0x7fffffff
#define MAXR 4.135166556742356f  // |log(16/1000)|

// ws offsets
#define WS_GCUR  0       // memset
#define WS_GHIST 64      // memset ends 37952
#define WS_GFLAG 37952
#define WS_GKEYS 38016   // ends 300160
#define WS_GBOX  300160  // ends 824448
#define WS_ZEND  37952   // memset [0, WS_ZEND)

__device__ __forceinline__ u64 pack_key(float score, unsigned fi) {
  return ((u64)__float_as_uint(score) << 32) | (u64)(0xFFFFFFFFu - fi);
}
__device__ __forceinline__ int bucket_of_bits(u32 sb) {
  return min(max((int)(sb >> 14) - HBASE, 0), NB - 1);
}
__device__ __forceinline__ u64 rdlane64(u64 v, int l) {
  u32 lo = (u32)__builtin_amdgcn_readlane((int)(u32)v, l);
  u32 hi = (u32)__builtin_amdgcn_readlane((int)(v >> 32), l);
  return ((u64)hi << 32) | lo;
}

// ---- wave64 reductions via DPP (VALU-only) ----
__device__ __forceinline__ float wred_max(float v) {
  int t;
#define STEPM(ctrl)                                                          \
  t = __builtin_amdgcn_update_dpp(__float_as_int(v), __float_as_int(v),      \
                                  (ctrl), 0xF, 0xF, false);                  \
  v = fmaxf(v, __int_as_float(t));
  STEPM(0x111) STEPM(0x112) STEPM(0x114) STEPM(0x118) STEPM(0x142) STEPM(0x143)
#undef STEPM
  return __int_as_float(__builtin_amdgcn_readlane(__float_as_int(v), 63));
}
__device__ __forceinline__ float wred_sum(float v) {
  int t;
#define STEPS(ctrl)                                                          \
  t = __builtin_amdgcn_update_dpp(0, __float_as_int(v), (ctrl), 0xF, 0xF,    \
                                  false);                                    \
  v = v + __int_as_float(t);
  STEPS(0x111) STEPS(0x112) STEPS(0x114) STEPS(0x118) STEPS(0x142) STEPS(0x143)
#undef STEPS
  return __int_as_float(__builtin_amdgcn_readlane(__float_as_int(v), 63));
}

// decode_one: used ONLY by nmsB (cold, never fetched when flag==0).
__device__ __forceinline__ float4 decode_one(
    u64 kk, const float* __restrict__ reg, const float* __restrict__ props,
    int b, float h, float w, float offscale) {
  unsigned fi = 0xFFFFFFFFu - (u32)kk;
  int n = (int)(fi / (unsigned)C_);
  int c = (int)(fi - (unsigned)n * (unsigned)C_);
  float4 p = ((const float4*)props)[b * N_ + n];
  const float* dl = reg + ((size_t)(b * N_ + n)) * (C_ * 4) + c * 4;
  float dx = dl[0] * 0.1f;
  float dy = dl[1] * 0.1f;
  float dw = fminf(fmaxf(dl[2] * 0.2f, -MAXR), MAXR);
  float dh = fminf(fmaxf(dl[3] * 0.2f, -MAXR), MAXR);
  float px = (p.x + p.z) * 0.5f, py = (p.y + p.w) * 0.5f;
  float pw = p.z - p.x, ph = p.w - p.y;
  float gx = px + pw * dx, gy = py + ph * dy;
  float gw = pw * expf(dw), gh = ph * expf(dh);
  float off = (float)c * offscale;  // cross-class IoU exactly 0 after offset
  return make_float4(fminf(fmaxf(gx - gw * 0.5f, 0.0f), w) + off,
                     fminf(fmaxf(gy - gh * 0.5f, 0.0f), h) + off,
                     fminf(fmaxf(gx + gw * 0.5f, 0.0f), w) + off,
                     fminf(fmaxf(gy + gh * 0.5f, 0.0f), h) + off);
}

// -- producer: softmax -> contiguous keys + DECODED boxes + fine histogram --
// (byte-identical to R21's cand, which measured ~6.5us)
__global__ __launch_bounds__(1024) void cand_kernel(
    const float* __restrict__ cls, const float* __restrict__ reg,
    const float* __restrict__ props, const int* __restrict__ hw,
    u64* __restrict__ gkeys, float4* __restrict__ gbox,
    u32* __restrict__ gcur, u32* __restrict__ ghist) {
  __shared__ int s_wc[16], s_woff[16];
  __shared__ int s_base;
  const int tid = threadIdx.x;
  const int wvi = tid >> 6, lane = tid & 63;
  const int blk = blockIdx.x;
  const int b = blk / BPI;
  const int n = (blk % BPI) * 16 + wvi;
  const float* lg = cls + (size_t)(b * N_ + n) * NCLS;
  float x0 = lg[lane];
  float x1 = (lane < 17) ? lg[64 + lane] : -3.0e38f;
  float mx = wred_max(fmaxf(x0, x1));
  float e0 = expf(x0 - mx);
  float e1 = (lane < 17) ? expf(x1 - mx) : 0.0f;
  float sum = wred_sum(e0 + e1);
  float sc0 = e0 / sum, sc1 = e1 / sum;
  bool p0 = sc0 > 0.05f;
  bool p1 = (lane < 16) && (sc1 > 0.05f);  // class 80 = background
  u64 m0 = __ballot(p0), m1 = __ballot(p1);
  int c0 = __popcll(m0);
  if (lane == 0) s_wc[wvi] = c0 + __popcll(m1);
  __syncthreads();
  if (tid == 0) {
    int acc = 0;
#pragma unroll
    for (int i = 0; i < 16; ++i) { s_woff[i] = acc; acc += s_wc[i]; }
    s_base = (acc > 0) ? (int)atomicAdd(&gcur[b], (u32)acc) : 0;
  }
  __syncthreads();
  const int base = s_base + s_woff[wvi];
  const u64 lt = (1ull << lane) - 1;
  u64* gk = gkeys + (size_t)b * CAPIMG;
  float4* gbx = gbox + (size_t)b * CAPIMG;
  u32* gh = ghist + (size_t)b * NBPAD;
  float hh = (float)hw[b * 2 + 0];
  float ww = (float)hw[b * 2 + 1];
  float offscale = fmaxf(hh, ww) + 1.0f;
  float4 p = ((const float4*)props)[b * N_ + n];
  float px = (p.x + p.z) * 0.5f, py = (p.y + p.w) * 0.5f;
  float pw = p.z - p.x, ph = p.w - p.y;
#pragma unroll 1
  for (int t = 0; t < 2; t++) {  // one code copy for both candidate slots
    bool pp = t ? p1 : p0;
    if (!pp) continue;
    float sc = t ? sc1 : sc0;
    int c = t ? (64 + lane) : lane;
    int slot = base + (t ? (c0 + __popcll(m1 & lt)) : __popcll(m0 & lt));
    atomicAdd(&gh[bucket_of_bits(__float_as_uint(sc))], 1u);
    if (slot < CAPIMG) {
      gk[slot] = pack_key(sc, (unsigned)(n * C_ + c));
      const float4 d4 =
          *(const float4*)(reg + ((size_t)(b * N_ + n)) * (C_ * 4) + c * 4);
      float dx = d4.x * 0.1f, dy = d4.y * 0.1f;
      float dw = fminf(fmaxf(d4.z * 0.2f, -MAXR), MAXR);
      float dh = fminf(fmaxf(d4.w * 0.2f, -MAXR), MAXR);
      float gx = px + pw * dx, gy = py + ph * dy;
      float gw = pw * expf(dw), gh2 = ph * expf(dh);
      float off = (float)c * offscale;
      gbx[slot] = make_float4(fminf(fmaxf(gx - gw * 0.5f, 0.0f), ww) + off,
                              fminf(fmaxf(gy - gh2 * 0.5f, 0.0f), hh) + off,
                              fminf(fmaxf(gx + gw * 0.5f, 0.0f), ww) + off,
                              fminf(fmaxf(gy + gh2 * 0.5f, 0.0f), hh) + off);
    }
  }
}

// ---------------- nms: minimal-instruction consumer (4 blocks) --------------
// LDS (24144 B): U u64[194]@0; SS u64[192]@1552; rb u64[192*4]@3088;
// bxA float4[192]@9232; s_hist u32[2368]@12304; Upos u32[192]@21776;
// rankA i32[192]@22544; outl i32[128]@23312; s_coarse i32[64]@23824;
// misc i32[16]@24080.
// misc: 0=T_A 2=S_A 3=Mtot 4=cnt 5=M 6=nk 7=ovf. Writers: tid<16 init
// (skips 5,7); tid512 -> 5,7; PhaseB lane0 -> 0,2,3; filter -> 4; scan -> 6.
__global__ __launch_bounds__(1024) void nms_kernel(
    const int* __restrict__ hw, const u64* __restrict__ gkeys,
    const float4* __restrict__ gbox, const u32* __restrict__ gcur,
    const u32* __restrict__ ghist, int* __restrict__ gflag,
    float* __restrict__ out) {
  __shared__ u64 lds8[3018];  // 24144 B
  char* bp = (char*)lds8;
  u64* U = (u64*)bp;
  u64* SS = (u64*)(bp + 1552);
  u64* rb = (u64*)(bp + 3088);
  float4* bxA = (float4*)(bp + 9232);
  u32* s_hist = (u32*)(bp + 12304);
  u32* Upos = (u32*)(bp + 21776);
  int* rankA = (int*)(bp + 22544);
  int* outl = (int*)(bp + 23312);
  int* s_coarse = (int*)(bp + 23824);
  int* misc = (int*)(bp + 24080);

  const int b = blockIdx.x, tid = threadIdx.x;
  const int wv = tid >> 6, lane = tid & 63;

  // ---- entry: stage ALL keys into regs (unguarded; latency hides under the
  //      ghist round below). ----
  const u64* keys = gkeys + (size_t)b * CAPIMG;
  u64 kreg[KPT];
#pragma unroll
  for (int r = 0; r < KPT; r++) kreg[r] = keys[tid + (r << 10)];

  if (tid < 16 && tid != 5 && tid != 7) misc[tid] = 0;
  if (tid >= NG && tid < 64) s_coarse[tid] = 0;
  if (tid == 512) {  // separate wave: cold gcur load overlaps ghist round
    u32 Mraw = gcur[b];
    misc[5] = min((int)Mraw, CAPIMG);
    misc[7] = (Mraw > (u32)CAPIMG) ? 1 : 0;
  }

  // ---- Round 1: ghist -> LDS + coarse sums (all waves). ----
  for (int g2 = wv; g2 < NG; g2 += 16) {
    int v = (int)ghist[b * NBPAD + ((g2 << 6) | lane)];
    s_hist[(g2 << 6) | lane] = (u32)v;
#pragma unroll
    for (int o = 32; o; o >>= 1) v += __shfl_xor(v, o);
    if (lane == 0) s_coarse[g2] = v;
  }
  __syncthreads();

  // ---- Phase B: wave 0 computes T_A (cum>=TARGET), S_A, Mtot. ----
  if (tid < 64) {
    int v = s_coarse[lane];
#pragma unroll
    for (int off = 1; off < 64; off <<= 1) {
      int src = lane + off;
      int o = __shfl(v, src < 64 ? src : 63);
      if (src < 64) v += o;
    }
    int Mtot = __shfl(v, 0);
    u64 pm = __ballot(v >= TARGET);
    int T_A = 0, S_A;
    if (pm) {
      int gs = 63 - __builtin_clzll(pm);
      int beyond = __shfl(v, gs + 1);
      int fv = (int)s_hist[(gs << 6) | lane];
#pragma unroll
      for (int off = 1; off < 64; off <<= 1) {
        int src = lane + off;
        int o = __shfl(fv, src < 64 ? src : 63);
        if (src < 64) fv += o;
      }
      int cum = beyond + fv;
      u64 pm2 = __ballot(cum >= TARGET);
      int tr = 63 - __builtin_clzll(pm2);
      T_A = (gs << 6) + tr;
      S_A = __shfl(cum, tr);
    } else {
      S_A = Mtot;
    }
    if (lane == 0) { misc[0] = T_A; misc[2] = S_A; misc[3] = Mtot; }
  }
  __syncthreads();

  const int T_A = misc[0], S_A = misc[2], Mtot = misc[3], M = misc[5];
  if (S_A > CAPA || misc[7] != 0) {
    if (tid == 0) gflag[b] = 1;  // nmsB handles this image
    return;
  }

  // ---- filter staged keys by T_A, ballot-compact into U/Upos (pure ALU). --
  {
    const u64 lt = (1ull << lane) - 1;
#pragma unroll 1
    for (int r = 0; r < KPT; r++) {
      int idx = tid + (r << 10);
      bool pr = (idx < M) && (bucket_of_bits((u32)(kreg[r] >> 32)) >= T_A);
      u64 mk = __ballot(pr);
      if (mk) {
        int wbase = 0;
        if (lane == 0) wbase = atomicAdd(&misc[4], __popcll(mk));
        wbase = __shfl(wbase, 0);
        if (pr) {
          int pos = wbase + __popcll(mk & lt);
          if (pos < CAPA) { U[pos] = kreg[r]; Upos[pos] = (u32)idx; }
        }
      }
    }
  }
  __syncthreads();
  int S = misc[4];
  if (S > CAPA) S = CAPA;
  if (tid == 0 && (S & 1)) U[S] = 0ULL;
  __syncthreads();

  // ---- rank-scatter sort (S<=192, <=96 iters) + box gather. ----
  if (tid < S) {
    u64 k1 = U[tid];
    int r1 = 0;
    const ulonglong2* Uu2 = (const ulonglong2*)U;
    int half = (S + 1) >> 1;
    for (int k = 0; k < half; k++) {
      ulonglong2 kk = Uu2[k];
      r1 += (kk.x > k1) + (kk.y > k1);
    }
    rankA[tid] = r1;
  }
  __syncthreads();
  if (tid < S) {
    int r1 = rankA[tid];
    SS[r1] = U[tid];
    bxA[r1] = gbox[(size_t)b * CAPIMG + Upos[tid]];
  }
  __syncthreads();

  // ---- IoU bit-matrix in 64x32 subtiles (<=12 over 16 waves). ----
  int nwords = (S + 63) >> 6;   // <= 3
  int nh = (S + 31) >> 5;       // <= 6
  {
    int ti = 0, rem = wv;
    bool have = false;
    while (ti < nwords) {
      int cnt = nh - 2 * ti;
      if (cnt <= 0) break;
      if (rem < cnt) { have = true; break; }
      rem -= cnt;
      ti++;
    }
    if (have) {
      int tjh = 2 * ti + rem;
      int i = (ti << 6) + lane;
      float4 bi4 = bxA[i];
      float ai = (bi4.z - bi4.x) * (bi4.w - bi4.y);
      u32 bits = 0;
      int jbase = tjh << 5;
      int jcount = min(32, S - jbase);
      for (int jj = 0; jj < jcount; jj++) {
        int j = jbase + jj;
        float4 bj = bxA[j];
        float aj = (bj.z - bj.x) * (bj.w - bj.y);
        float iw = fmaxf(fminf(bi4.z, bj.z) - fmaxf(bi4.x, bj.x), 0.0f);
        float ih = fmaxf(fminf(bi4.w, bj.w) - fmaxf(bi4.y, bj.y), 0.0f);
        float inter = iw * ih;
        float iou = inter / (ai + aj - inter + 1e-6f);
        if (j > i && iou > 0.5f) bits |= (1u << jj);
      }
      if (i < S) ((u32*)rb)[i * 8 + tjh] = bits;
    }
  }
  __syncthreads();

  // ---- register/readlane greedy scan (wave 0), 3 chunks. Words w<c of a
  //      row are semantically zero (suppression only for j>q); halves >= nh
  //      are garbage but only affect candidates >= S (alive-masked 0). ----
  if (tid < 64) {
    u64 R[3][3];
#pragma unroll
    for (int c2 = 0; c2 < 3; c2++) {
#pragma unroll
      for (int w2 = 0; w2 < 3; w2++) {
        R[c2][w2] = (w2 >= c2) ? rb[((c2 << 6) + lane) * 4 + w2] : 0ull;
      }
    }
    u64 al[3];
#pragma unroll
    for (int w2 = 0; w2 < 3; w2++) {
      int lo = w2 << 6;
      al[w2] = (S > lo) ? ((S - lo >= 64) ? ~0ull : ((1ull << (S - lo)) - 1))
                        : 0ull;
    }
    int nk = 0;
#pragma unroll
    for (int c2 = 0; c2 < 3; c2++) {
      u64 a = al[c2];
      while (a) {
        int i = __builtin_ctzll(a);  // uniform across the wave
        if (lane == 0) outl[nk] = (c2 << 6) + i;
        nk++;
        if (nk >= MAXDET) break;
        a &= a - 1;                      // drop bit i
        a &= ~rdlane64(R[c2][c2], i);    // in-chunk suppression
#pragma unroll
        for (int w2 = c2 + 1; w2 < 3; w2++)
          al[w2] &= ~rdlane64(R[c2][w2], i);  // cross-chunk suppression
      }
      if (nk >= MAXDET) break;
    }
    if (lane == 0) misc[6] = nk;
  }
  __syncthreads();
  const int nkept = misc[6];
  bool modeB = (nkept < MAXDET && S < Mtot && S < KPRE);
  if (tid == 0) gflag[b] = modeB ? 1 : 0;
  if (modeB) return;

  // Output: boxes [B,100,4] | scores [B,100] | labels [B,100].
  float h = (float)hw[b * 2 + 0];
  float w = (float)hw[b * 2 + 1];
  float offscale = fmaxf(h, w) + 1.0f;
  float* oBox = out;
  float* oSc = out + B_ * MAXDET * 4;
  float* oLb = out + B_ * MAXDET * 5;
  if (tid < MAXDET) {
    float4 bb = make_float4(0.0f, 0.0f, 0.0f, 0.0f);
    float sv = 0.0f, lv = -1.0f;
    if (tid < nkept) {
      int idx = outl[tid];
      u64 kk = SS[idx];
      sv = __uint_as_float((u32)(kk >> 32));
      unsigned fi = 0xFFFFFFFFu - (u32)kk;
      int c = (int)(fi % (unsigned)C_);
      float off = (float)c * offscale;
      float4 ob = bxA[idx];
      bb = make_float4(ob.x - off, ob.y - off, ob.z - off, ob.w - off);
      lv = (float)c;
    }
    oBox[(b * MAXDET + tid) * 4 + 0] = bb.x;
    oBox[(b * MAXDET + tid) * 4 + 1] = bb.y;
    oBox[(b * MAXDET + tid) * 4 + 2] = bb.z;
    oBox[(b * MAXDET + tid) * 4 + 3] = bb.w;
    oSc[b * MAXDET + tid] = sv;
    oLb[b * MAXDET + tid] = lv;
  }
}

// ---------------- nmsB: exact fallback (flag-gated, contiguous) -------------
__global__ __launch_bounds__(1024) void nmsB_kernel(
    const float* __restrict__ reg, const float* __restrict__ props,
    const int* __restrict__ hw, const u64* __restrict__ gkeys,
    const u32* __restrict__ gcur, const int* __restrict__ gflag,
    float* __restrict__ out) {
  const int b = blockIdx.x, tid = threadIdx.x;
  if (gflag[b] == 0) return;  // block-uniform fast exit (the normal case)

  __shared__ u64 lds8[7952];
  char* bp = (char*)lds8;
  u32* hist = (u32*)(bp + 0);          // [0,9472)
  u64* U2 = (u64*)(bp + 9472);         // 2048 keys
  u64* SSB = (u64*)(bp + 25856);       // 2048 sorted
  int* outl = (int*)(bp + 42240);      // 128
  int* misc = (int*)(bp + 42752);      // 16
  const int lane = tid & 63;

  float h = (float)hw[b * 2 + 0];
  float w = (float)hw[b * 2 + 1];
  float offscale = fmaxf(h, w) + 1.0f;

  const u64* keys = gkeys + (size_t)b * CAPIMG;
  const int M = min((int)gcur[b], CAPIMG);

  for (int i = tid; i < NBPAD; i += 1024) hist[i] = 0;
  if (tid < 16) misc[tid] = 0;
  __syncthreads();

  // Histogram from contiguous keys.
  for (int idx = tid; idx < M; idx += 1024) {
    u64 key = keys[idx];
    int bi = min(max((int)(key >> KSHIFT) - HBASE, 0), NB - 1);
    atomicAdd(&hist[bi], 1u);
  }
  __syncthreads();

  // T_B: serial suffix walk (cold path).
  if (tid == 0) {
    int acc = 0, tb = 0;
    for (int bi = NB - 1; bi >= 0; bi--) {
      acc += (int)hist[bi];
      if (acc >= KPRE) { tb = bi; break; }
    }
    if (acc > CAPB) tb = min(tb + 1, NB - 1);  // fat-bucket guard
    misc[1] = tb;
    misc[4] = 0;
  }
  __syncthreads();
  int T_B = misc[1];

  // Compact bucket >= T_B into U2 (ballot-aggregated).
  for (int idx0 = 0; idx0 < M; idx0 += 1024) {
    int idx = idx0 + tid;
    bool pred = false;
    u64 key = 0;
    if (idx < M) {
      key = keys[idx];
      int bi = min(max((int)(key >> KSHIFT) - HBASE, 0), NB - 1);
      pred = (bi >= T_B);
    }
    u64 mk = __ballot(pred);
    if (mk) {
      int wbase = 0;
      if (lane == 0) wbase = atomicAdd(&misc[4], __popcll(mk));
      wbase = __shfl(wbase, 0);
      if (pred) {
        int pos = wbase + __popcll(mk & ((1ull << lane) - 1));
        if (pos < CAPB) U2[pos] = key;
      }
    }
  }
  __syncthreads();
  int S = misc[4];
  if (S > CAPB) S = CAPB;
  {  // rank-scatter sort, 2 keys/thread
    int j1 = tid, j2 = tid + 1024;
    u64 k1 = (j1 < S) ? U2[j1] : 0ULL;
    u64 k2 = (j2 < S) ? U2[j2] : 0ULL;
    int r1 = 0, r2 = 0;
    for (int k = 0; k < S; k++) {
      u64 kk = U2[k];
      r1 += (kk > k1);
      r2 += (kk > k2);
    }
    __syncthreads();
    if (j1 < S) SSB[r1] = k1;
    if (j2 < S) SSB[r2] = k2;
  }
  __syncthreads();
  int K = (S < KPRE) ? S : KPRE;  // exact top-2000 (or all if fewer)
  // NMS with per-thread register boxes.
  int j1 = tid, j2 = tid + 1024;
  bool kp1 = (j1 < K), kp2 = (j2 < K);
  float4 bb1 = kp1 ? decode_one(SSB[j1], reg, props, b, h, w, offscale)
                   : make_float4(0, 0, 0, 0);
  float4 bb2 = kp2 ? decode_one(SSB[j2], reg, props, b, h, w, offscale)
                   : make_float4(0, 0, 0, 0);
  int nk = 0;
  if (K > 0) {
    int i = 0;
    for (;;) {
      if (tid == 0) { outl[nk] = i; misc[5] = K; }
      nk++;
      if (nk >= MAXDET) break;
      __syncthreads();
      float4 tb = decode_one(SSB[i], reg, props, b, h, w, offscale);
      float ai = (tb.z - tb.x) * (tb.w - tb.y);
      int ln = K;
      if (kp1 && j1 > i) {
        float aj = (bb1.z - bb1.x) * (bb1.w - bb1.y);
        float iw = fmaxf(fminf(tb.z, bb1.z) - fmaxf(tb.x, bb1.x), 0.0f);
        float ih = fmaxf(fminf(tb.w, bb1.w) - fmaxf(tb.y, bb1.y), 0.0f);
        float inter = iw * ih;
        float iou = inter / (ai + aj - inter + 1e-6f);
        if (iou > 0.5f) kp1 = false;
        else ln = min(ln, j1);
      }
      if (kp2 && j2 > i) {
        float aj = (bb2.z - bb2.x) * (bb2.w - bb2.y);
        float iw = fmaxf(fminf(tb.z, bb2.z) - fmaxf(tb.x, bb2.x), 0.0f);
        float ih = fmaxf(fminf(tb.w, bb2.w) - fmaxf(tb.y, bb2.y), 0.0f);
        float inter = iw * ih;
        float iou = inter / (ai + aj - inter + 1e-6f);
        if (iou > 0.5f) kp2 = false;
        else ln = min(ln, j2);
      }
#pragma unroll
      for (int off = 32; off; off >>= 1) ln = min(ln, __shfl_xor(ln, off));
      if ((tid & 63) == 0 && ln < K) atomicMin(&misc[5], ln);
      __syncthreads();
      int ni = misc[5];
      __syncthreads();
      if (ni >= K) break;
      i = ni;
    }
  }
  if (tid == 0) misc[6] = nk;
  __syncthreads();
  int nkept = misc[6];

  float* oBox = out;
  float* oSc = out + B_ * MAXDET * 4;
  float* oLb = out + B_ * MAXDET * 5;
  for (int k2 = tid; k2 < MAXDET; k2 += 1024) {
    float4 bb = make_float4(0.0f, 0.0f, 0.0f, 0.0f);
    float sv = 0.0f, lv = -1.0f;
    if (k2 < nkept) {
      int idx = outl[k2];
      u64 kk = SSB[idx];
      sv = __uint_as_float((u32)(kk >> 32));
      unsigned fi = 0xFFFFFFFFu - (u32)kk;
      int c = (int)(fi % (unsigned)C_);
      float off = (float)c * offscale;
      float4 ob = decode_one(kk, reg, props, b, h, w, offscale);
      bb = make_float4(ob.x - off, ob.y - off, ob.z - off, ob.w - off);
      lv = (float)c;
    }
    oBox[(b * MAXDET + k2) * 4 + 0] = bb.x;
    oBox[(b * MAXDET + k2) * 4 + 1] = bb.y;
    oBox[(b * MAXDET + k2) * 4 + 2] = bb.z;
    oBox[(b * MAXDET + k2) * 4 + 3] = bb.w;
    oSc[b * MAXDET + k2] = sv;
    oLb[b * MAXDET + k2] = lv;
  }
}

extern "C" void kernel_launch(void* const* d_in, const int* in_sizes, int n_in,
                              void* d_out, int out_size, void* d_ws, size_t ws_size,
                              hipStream_t stream) {
  const float* cls = (const float*)d_in[0];    // [B,N,81] f32
  const float* reg = (const float*)d_in[1];    // [B,N,320] f32
  const float* props = (const float*)d_in[2];  // [B,N,4] f32
  const int* hw = (const int*)d_in[3];         // [B,2] i32
  float* out = (float*)d_out;                  // 2400 f32

  u32* gcur = (u32*)((char*)d_ws + WS_GCUR);
  u32* ghist = (u32*)((char*)d_ws + WS_GHIST);
  int* gflag = (int*)((char*)d_ws + WS_GFLAG);
  u64* gkeys = (u64*)((char*)d_ws + WS_GKEYS);
  float4* gbox = (float4*)((char*)d_ws + WS_GBOX);

  hipMemsetAsync(d_ws, 0, WS_ZEND, stream);
  cand_kernel<<<B_ * BPI, 1024, 0, stream>>>(cls, reg, props, hw,
                                             gkeys, gbox, gcur, ghist);
  nms_kernel<<<B_, 1024, 0, stream>>>(hw, gkeys, gbox, gcur, ghist, gflag, out);
  nmsB_kernel<<<B_, 1024, 0, stream>>>(reg, props, hw, gkeys, gcur, gflag, out);
}

// Round 13
// 95.270 us; speedup vs baseline: 2.7039x; 1.0328x over previous
//
#include <hip/hip_runtime.h>

// RoI2Det, R24 = R23 (98.4us) + two more serial-instruction cuts.
// Mechanism (R20-R23, twice-confirmed): core clock ~500MHz during
// micro-kernels (DVFS parked by HBM-bound poison fills) => 4-block consumer
// critical path ~ serial instruction count. R21 (reg/readlane scan) -5.3us,
// R23 (TARGET128/CAPA192 + 32-wide IoU + reg-staged keys) -5.9us.
// R22 LESSON (kept): never put agent-scope fences on the 500-block path.
//
// R24 cuts:
//  1. Rank-sort split 4 ways: 4 threads/key, partial ranks merged via LDS
//     atomicAdd (commutative -> deterministic). Serial length 96 -> ~26.
//  2. Greedy scan: cross-chunk suppression DEFERRED to chunk end as one
//     batched wave-OR reduction per (chunk,word) (greedy order: chunk-c
//     keepers are fully decided before any chunk-(c+1) candidate is
//     considered, so batching is semantically identical). Inner loop is now
//     ctz -> record -> in-chunk andn (~10 inst/keeper).
//
// Exactness: mode A sorts the exact top-S (S in [TARGET,CAPA]) selected by
// the monotone fine histogram. Guards (M>CAPIMG, S_A>CAPA, nkept<100 with
// uncovered candidates) route to nmsB which redoes everything exactly.
//
// ws: [0,16) u32 gcur[4] (memset); [64,37952) u32 ghist[4][2368] (memset);
//     [37952,37968) int gflag[4]; [38016,300160) u64 gkeys[4][8192];
//     [300160,824448) float4 gbox[4][8192].
// key = (score_bits<<32) | (0xFFFFFFFF - flat_idx): desc order == lax.top_k.

typedef unsigned long long u64;
typedef unsigned int u32;

#define B_ 4
#define N_ 2000
#define C_ 80
#define NCLS 81
#define KPRE 2000
#define MAXDET 100
#define TARGET 128      // mode-A prefix floor (rank_100 ~ 110 observed)
#define NB 2312         // fine score buckets
#define NBPAD 2368      // 37*64
#define NG 37
#define HBASE 0xF500
#define KSHIFT 46       // key>>46 == score_bits>>14
#define CAPA 192
#define CAPB 2048
#define CAPIMG 8192     // per-image contiguous key cap (expected M ~ 4500)
#define KPT 8           // staged key rounds (8*1024 = CAPIMG)
#define BPI 125         // producer blocks per image
#define BIGI 0x7fffffff
#define MAXR 4.135166556742356f  // |log(16/1000)|

// ws offsets
#define WS_GCUR  0       // memset
#define WS_GHIST 64      // memset ends 37952
#define WS_GFLAG 37952
#define WS_GKEYS 38016   // ends 300160
#define WS_GBOX  300160  // ends 824448
#define WS_ZEND  37952   // memset [0, WS_ZEND)

__device__ __forceinline__ u64 pack_key(float score, unsigned fi) {
  return ((u64)__float_as_uint(score) << 32) | (u64)(0xFFFFFFFFu - fi);
}
__device__ __forceinline__ int bucket_of_bits(u32 sb) {
  return min(max((int)(sb >> 14) - HBASE, 0), NB - 1);
}
__device__ __forceinline__ u64 rdlane64(u64 v, int l) {
  u32 lo = (u32)__builtin_amdgcn_readlane((int)(u32)v, l);
  u32 hi = (u32)__builtin_amdgcn_readlane((int)(v >> 32), l);
  return ((u64)hi << 32) | lo;
}

// ---- wave64 reductions via DPP (VALU-only) ----
__device__ __forceinline__ float wred_max(float v) {
  int t;
#define STEPM(ctrl)                                                          \
  t = __builtin_amdgcn_update_dpp(__float_as_int(v), __float_as_int(v),      \
                                  (ctrl), 0xF, 0xF, false);                  \
  v = fmaxf(v, __int_as_float(t));
  STEPM(0x111) STEPM(0x112) STEPM(0x114) STEPM(0x118) STEPM(0x142) STEPM(0x143)
#undef STEPM
  return __int_as_float(__builtin_amdgcn_readlane(__float_as_int(v), 63));
}
__device__ __forceinline__ float wred_sum(float v) {
  int t;
#define STEPS(ctrl)                                                          \
  t = __builtin_amdgcn_update_dpp(0, __float_as_int(v), (ctrl), 0xF, 0xF,    \
                                  false);                                    \
  v = v + __int_as_float(t);
  STEPS(0x111) STEPS(0x112) STEPS(0x114) STEPS(0x118) STEPS(0x142) STEPS(0x143)
#undef STEPS
  return __int_as_float(__builtin_amdgcn_readlane(__float_as_int(v), 63));
}

// decode_one: used ONLY by nmsB (cold, never fetched when flag==0).
__device__ __forceinline__ float4 decode_one(
    u64 kk, const float* __restrict__ reg, const float* __restrict__ props,
    int b, float h, float w, float offscale) {
  unsigned fi = 0xFFFFFFFFu - (u32)kk;
  int n = (int)(fi / (unsigned)C_);
  int c = (int)(fi - (unsigned)n * (unsigned)C_);
  float4 p = ((const float4*)props)[b * N_ + n];
  const float* dl = reg + ((size_t)(b * N_ + n)) * (C_ * 4) + c * 4;
  float dx = dl[0] * 0.1f;
  float dy = dl[1] * 0.1f;
  float dw = fminf(fmaxf(dl[2] * 0.2f, -MAXR), MAXR);
  float dh = fminf(fmaxf(dl[3] * 0.2f, -MAXR), MAXR);
  float px = (p.x + p.z) * 0.5f, py = (p.y + p.w) * 0.5f;
  float pw = p.z - p.x, ph = p.w - p.y;
  float gx = px + pw * dx, gy = py + ph * dy;
  float gw = pw * expf(dw), gh = ph * expf(dh);
  float off = (float)c * offscale;  // cross-class IoU exactly 0 after offset
  return make_float4(fminf(fmaxf(gx - gw * 0.5f, 0.0f), w) + off,
                     fminf(fmaxf(gy - gh * 0.5f, 0.0f), h) + off,
                     fminf(fmaxf(gx + gw * 0.5f, 0.0f), w) + off,
                     fminf(fmaxf(gy + gh * 0.5f, 0.0f), h) + off);
}

// -- producer: softmax -> contiguous keys + DECODED boxes + fine histogram --
// (byte-identical to R21/R23's cand, ~6.5us)
__global__ __launch_bounds__(1024) void cand_kernel(
    const float* __restrict__ cls, const float* __restrict__ reg,
    const float* __restrict__ props, const int* __restrict__ hw,
    u64* __restrict__ gkeys, float4* __restrict__ gbox,
    u32* __restrict__ gcur, u32* __restrict__ ghist) {
  __shared__ int s_wc[16], s_woff[16];
  __shared__ int s_base;
  const int tid = threadIdx.x;
  const int wvi = tid >> 6, lane = tid & 63;
  const int blk = blockIdx.x;
  const int b = blk / BPI;
  const int n = (blk % BPI) * 16 + wvi;
  const float* lg = cls + (size_t)(b * N_ + n) * NCLS;
  float x0 = lg[lane];
  float x1 = (lane < 17) ? lg[64 + lane] : -3.0e38f;
  float mx = wred_max(fmaxf(x0, x1));
  float e0 = expf(x0 - mx);
  float e1 = (lane < 17) ? expf(x1 - mx) : 0.0f;
  float sum = wred_sum(e0 + e1);
  float sc0 = e0 / sum, sc1 = e1 / sum;
  bool p0 = sc0 > 0.05f;
  bool p1 = (lane < 16) && (sc1 > 0.05f);  // class 80 = background
  u64 m0 = __ballot(p0), m1 = __ballot(p1);
  int c0 = __popcll(m0);
  if (lane == 0) s_wc[wvi] = c0 + __popcll(m1);
  __syncthreads();
  if (tid == 0) {
    int acc = 0;
#pragma unroll
    for (int i = 0; i < 16; ++i) { s_woff[i] = acc; acc += s_wc[i]; }
    s_base = (acc > 0) ? (int)atomicAdd(&gcur[b], (u32)acc) : 0;
  }
  __syncthreads();
  const int base = s_base + s_woff[wvi];
  const u64 lt = (1ull << lane) - 1;
  u64* gk = gkeys + (size_t)b * CAPIMG;
  float4* gbx = gbox + (size_t)b * CAPIMG;
  u32* gh = ghist + (size_t)b * NBPAD;
  float hh = (float)hw[b * 2 + 0];
  float ww = (float)hw[b * 2 + 1];
  float offscale = fmaxf(hh, ww) + 1.0f;
  float4 p = ((const float4*)props)[b * N_ + n];
  float px = (p.x + p.z) * 0.5f, py = (p.y + p.w) * 0.5f;
  float pw = p.z - p.x, ph = p.w - p.y;
#pragma unroll 1
  for (int t = 0; t < 2; t++) {  // one code copy for both candidate slots
    bool pp = t ? p1 : p0;
    if (!pp) continue;
    float sc = t ? sc1 : sc0;
    int c = t ? (64 + lane) : lane;
    int slot = base + (t ? (c0 + __popcll(m1 & lt)) : __popcll(m0 & lt));
    atomicAdd(&gh[bucket_of_bits(__float_as_uint(sc))], 1u);
    if (slot < CAPIMG) {
      gk[slot] = pack_key(sc, (unsigned)(n * C_ + c));
      const float4 d4 =
          *(const float4*)(reg + ((size_t)(b * N_ + n)) * (C_ * 4) + c * 4);
      float dx = d4.x * 0.1f, dy = d4.y * 0.1f;
      float dw = fminf(fmaxf(d4.z * 0.2f, -MAXR), MAXR);
      float dh = fminf(fmaxf(d4.w * 0.2f, -MAXR), MAXR);
      float gx = px + pw * dx, gy = py + ph * dy;
      float gw = pw * expf(dw), gh2 = ph * expf(dh);
      float off = (float)c * offscale;
      gbx[slot] = make_float4(fminf(fmaxf(gx - gw * 0.5f, 0.0f), ww) + off,
                              fminf(fmaxf(gy - gh2 * 0.5f, 0.0f), hh) + off,
                              fminf(fmaxf(gx + gw * 0.5f, 0.0f), ww) + off,
                              fminf(fmaxf(gy + gh2 * 0.5f, 0.0f), hh) + off);
    }
  }
}

// ---------------- nms: minimal-instruction consumer (4 blocks) --------------
// LDS (24144 B): U u64[194]@0; SS u64[192]@1552; rb u64[192*4]@3088;
// bxA float4[192]@9232; s_hist u32[2368]@12304; Upos u32[192]@21776;
// rankA i32[192]@22544; outl i32[128]@23312; s_coarse i32[64]@23824;
// misc i32[16]@24080.
// misc: 0=T_A 2=S_A 3=Mtot 4=cnt 5=M 6=nk 7=ovf. Writers: tid<16 init
// (skips 5,7); tid512 -> 5,7; PhaseB lane0 -> 0,2,3; filter -> 4; scan -> 6.
__global__ __launch_bounds__(1024) void nms_kernel(
    const int* __restrict__ hw, const u64* __restrict__ gkeys,
    const float4* __restrict__ gbox, const u32* __restrict__ gcur,
    const u32* __restrict__ ghist, int* __restrict__ gflag,
    float* __restrict__ out) {
  __shared__ u64 lds8[3018];  // 24144 B
  char* bp = (char*)lds8;
  u64* U = (u64*)bp;
  u64* SS = (u64*)(bp + 1552);
  u64* rb = (u64*)(bp + 3088);
  float4* bxA = (float4*)(bp + 9232);
  u32* s_hist = (u32*)(bp + 12304);
  u32* Upos = (u32*)(bp + 21776);
  int* rankA = (int*)(bp + 22544);
  int* outl = (int*)(bp + 23312);
  int* s_coarse = (int*)(bp + 23824);
  int* misc = (int*)(bp + 24080);

  const int b = blockIdx.x, tid = threadIdx.x;
  const int wv = tid >> 6, lane = tid & 63;

  // ---- entry: stage ALL keys into regs (unguarded; latency hides under the
  //      ghist round below). ----
  const u64* keys = gkeys + (size_t)b * CAPIMG;
  u64 kreg[KPT];
#pragma unroll
  for (int r = 0; r < KPT; r++) kreg[r] = keys[tid + (r << 10)];

  if (tid < 16 && tid != 5 && tid != 7) misc[tid] = 0;
  if (tid >= NG && tid < 64) s_coarse[tid] = 0;
  if (tid >= 64 && tid < 64 + CAPA) rankA[tid - 64] = 0;  // for 4-way sort
  if (tid == 512) {  // separate wave: cold gcur load overlaps ghist round
    u32 Mraw = gcur[b];
    misc[5] = min((int)Mraw, CAPIMG);
    misc[7] = (Mraw > (u32)CAPIMG) ? 1 : 0;
  }

  // ---- Round 1: ghist -> LDS + coarse sums (all waves). ----
  for (int g2 = wv; g2 < NG; g2 += 16) {
    int v = (int)ghist[b * NBPAD + ((g2 << 6) | lane)];
    s_hist[(g2 << 6) | lane] = (u32)v;
#pragma unroll
    for (int o = 32; o; o >>= 1) v += __shfl_xor(v, o);
    if (lane == 0) s_coarse[g2] = v;
  }
  __syncthreads();

  // ---- Phase B: wave 0 computes T_A (cum>=TARGET), S_A, Mtot. ----
  if (tid < 64) {
    int v = s_coarse[lane];
#pragma unroll
    for (int off = 1; off < 64; off <<= 1) {
      int src = lane + off;
      int o = __shfl(v, src < 64 ? src : 63);
      if (src < 64) v += o;
    }
    int Mtot = __shfl(v, 0);
    u64 pm = __ballot(v >= TARGET);
    int T_A = 0, S_A;
    if (pm) {
      int gs = 63 - __builtin_clzll(pm);
      int beyond = __shfl(v, gs + 1);
      int fv = (int)s_hist[(gs << 6) | lane];
#pragma unroll
      for (int off = 1; off < 64; off <<= 1) {
        int src = lane + off;
        int o = __shfl(fv, src < 64 ? src : 63);
        if (src < 64) fv += o;
      }
      int cum = beyond + fv;
      u64 pm2 = __ballot(cum >= TARGET);
      int tr = 63 - __builtin_clzll(pm2);
      T_A = (gs << 6) + tr;
      S_A = __shfl(cum, tr);
    } else {
      S_A = Mtot;
    }
    if (lane == 0) { misc[0] = T_A; misc[2] = S_A; misc[3] = Mtot; }
  }
  __syncthreads();

  const int T_A = misc[0], S_A = misc[2], Mtot = misc[3], M = misc[5];
  if (S_A > CAPA || misc[7] != 0) {
    if (tid == 0) gflag[b] = 1;  // nmsB handles this image
    return;
  }

  // ---- filter staged keys by T_A, ballot-compact into U/Upos (pure ALU). --
  {
    const u64 lt = (1ull << lane) - 1;
#pragma unroll 1
    for (int r = 0; r < KPT; r++) {
      int idx = tid + (r << 10);
      bool pr = (idx < M) && (bucket_of_bits((u32)(kreg[r] >> 32)) >= T_A);
      u64 mk = __ballot(pr);
      if (mk) {
        int wbase = 0;
        if (lane == 0) wbase = atomicAdd(&misc[4], __popcll(mk));
        wbase = __shfl(wbase, 0);
        if (pr) {
          int pos = wbase + __popcll(mk & lt);
          if (pos < CAPA) { U[pos] = kreg[r]; Upos[pos] = (u32)idx; }
        }
      }
    }
  }
  __syncthreads();
  int S = misc[4];
  if (S > CAPA) S = CAPA;
  if (tid == 0 && (S & 1)) U[S] = 0ULL;
  __syncthreads();

  // ---- rank-scatter sort, 4 threads/key (<=26 iters each; partial ranks
  //      merged via LDS atomicAdd — commutative, deterministic). ----
  {
    int key = tid >> 2, part = tid & 3;
    if (key < S) {
      u64 k1 = U[key];
      const ulonglong2* Uu2 = (const ulonglong2*)U;
      int half = (S + 1) >> 1;
      int qlen = (half + 3) >> 2;
      int k0 = part * qlen;
      int kend = min(k0 + qlen, half);
      int r = 0;
      for (int k = k0; k < kend; k++) {
        ulonglong2 kk = Uu2[k];
        r += (kk.x > k1) + (kk.y > k1);
      }
      if (r) atomicAdd(&rankA[key], r);
    }
  }
  __syncthreads();
  if (tid < S) {
    int r1 = rankA[tid];
    SS[r1] = U[tid];
    bxA[r1] = gbox[(size_t)b * CAPIMG + Upos[tid]];
  }
  __syncthreads();

  // ---- IoU bit-matrix in 64x32 subtiles (<=12 over 16 waves). ----
  int nwords = (S + 63) >> 6;   // <= 3
  int nh = (S + 31) >> 5;       // <= 6
  {
    int ti = 0, rem = wv;
    bool have = false;
    while (ti < nwords) {
      int cnt = nh - 2 * ti;
      if (cnt <= 0) break;
      if (rem < cnt) { have = true; break; }
      rem -= cnt;
      ti++;
    }
    if (have) {
      int tjh = 2 * ti + rem;
      int i = (ti << 6) + lane;
      float4 bi4 = bxA[i];
      float ai = (bi4.z - bi4.x) * (bi4.w - bi4.y);
      u32 bits = 0;
      int jbase = tjh << 5;
      int jcount = min(32, S - jbase);
      for (int jj = 0; jj < jcount; jj++) {
        int j = jbase + jj;
        float4 bj = bxA[j];
        float aj = (bj.z - bj.x) * (bj.w - bj.y);
        float iw = fmaxf(fminf(bi4.z, bj.z) - fmaxf(bi4.x, bj.x), 0.0f);
        float ih = fmaxf(fminf(bi4.w, bj.w) - fmaxf(bi4.y, bj.y), 0.0f);
        float inter = iw * ih;
        float iou = inter / (ai + aj - inter + 1e-6f);
        if (j > i && iou > 0.5f) bits |= (1u << jj);
      }
      if (i < S) ((u32*)rb)[i * 8 + tjh] = bits;
    }
  }
  __syncthreads();

  // ---- register greedy scan (wave 0), 3 chunks, DEFERRED cross-chunk
  //      suppression. Greedy order: chunk-c keepers are fully decided before
  //      any chunk-(c+1) candidate, so batching their cross-chunk masks into
  //      one wave-OR reduction per word is semantically identical. ----
  if (tid < 64) {
    u64 R[3][3];
#pragma unroll
    for (int c2 = 0; c2 < 3; c2++) {
#pragma unroll
      for (int w2 = 0; w2 < 3; w2++) {
        R[c2][w2] = (w2 >= c2) ? rb[((c2 << 6) + lane) * 4 + w2] : 0ull;
      }
    }
    u64 al[3];
#pragma unroll
    for (int w2 = 0; w2 < 3; w2++) {
      int lo = w2 << 6;
      al[w2] = (S > lo) ? ((S - lo >= 64) ? ~0ull : ((1ull << (S - lo)) - 1))
                        : 0ull;
    }
    int nk = 0;
#pragma unroll
    for (int c2 = 0; c2 < 3; c2++) {
      u64 a = al[c2];
      u64 kmask = 0;  // uniform: keeper lanes of this chunk
      while (a) {
        int i = __builtin_ctzll(a);  // uniform across the wave
        if (lane == 0) outl[nk] = (c2 << 6) + i;
        kmask |= (1ull << i);
        nk++;
        if (nk >= MAXDET) break;
        a &= a - 1;                    // drop bit i
        a &= ~rdlane64(R[c2][c2], i);  // in-chunk suppression only
      }
      if (nk >= MAXDET) break;
      // batched cross-chunk suppression: OR over keeper lanes' row words.
#pragma unroll
      for (int w2 = c2 + 1; w2 < 3; w2++) {
        u64 contrib = ((kmask >> lane) & 1ull) ? R[c2][w2] : 0ull;
#pragma unroll
        for (int o = 32; o; o >>= 1) contrib |= __shfl_xor(contrib, o);
        al[w2] &= ~contrib;
      }
    }
    if (lane == 0) misc[6] = nk;
  }
  __syncthreads();
  const int nkept = misc[6];
  bool modeB = (nkept < MAXDET && S < Mtot && S < KPRE);
  if (tid == 0) gflag[b] = modeB ? 1 : 0;
  if (modeB) return;

  // Output: boxes [B,100,4] | scores [B,100] | labels [B,100].
  float h = (float)hw[b * 2 + 0];
  float w = (float)hw[b * 2 + 1];
  float offscale = fmaxf(h, w) + 1.0f;
  float* oBox = out;
  float* oSc = out + B_ * MAXDET * 4;
  float* oLb = out + B_ * MAXDET * 5;
  if (tid < MAXDET) {
    float4 bb = make_float4(0.0f, 0.0f, 0.0f, 0.0f);
    float sv = 0.0f, lv = -1.0f;
    if (tid < nkept) {
      int idx = outl[tid];
      u64 kk = SS[idx];
      sv = __uint_as_float((u32)(kk >> 32));
      unsigned fi = 0xFFFFFFFFu - (u32)kk;
      int c = (int)(fi % (unsigned)C_);
      float off = (float)c * offscale;
      float4 ob = bxA[idx];
      bb = make_float4(ob.x - off, ob.y - off, ob.z - off, ob.w - off);
      lv = (float)c;
    }
    oBox[(b * MAXDET + tid) * 4 + 0] = bb.x;
    oBox[(b * MAXDET + tid) * 4 + 1] = bb.y;
    oBox[(b * MAXDET + tid) * 4 + 2] = bb.z;
    oBox[(b * MAXDET + tid) * 4 + 3] = bb.w;
    oSc[b * MAXDET + tid] = sv;
    oLb[b * MAXDET + tid] = lv;
  }
}

// ---------------- nmsB: exact fallback (flag-gated, contiguous) -------------
__global__ __launch_bounds__(1024) void nmsB_kernel(
    const float* __restrict__ reg, const float* __restrict__ props,
    const int* __restrict__ hw, const u64* __restrict__ gkeys,
    const u32* __restrict__ gcur, const int* __restrict__ gflag,
    float* __restrict__ out) {
  const int b = blockIdx.x, tid = threadIdx.x;
  if (gflag[b] == 0) return;  // block-uniform fast exit (the normal case)

  __shared__ u64 lds8[7952];
  char* bp = (char*)lds8;
  u32* hist = (u32*)(bp + 0);          // [0,9472)
  u64* U2 = (u64*)(bp + 9472);         // 2048 keys
  u64* SSB = (u64*)(bp + 25856);       // 2048 sorted
  int* outl = (int*)(bp + 42240);      // 128
  int* misc = (int*)(bp + 42752);      // 16
  const int lane = tid & 63;

  float h = (float)hw[b * 2 + 0];
  float w = (float)hw[b * 2 + 1];
  float offscale = fmaxf(h, w) + 1.0f;

  const u64* keys = gkeys + (size_t)b * CAPIMG;
  const int M = min((int)gcur[b], CAPIMG);

  for (int i = tid; i < NBPAD; i += 1024) hist[i] = 0;
  if (tid < 16) misc[tid] = 0;
  __syncthreads();

  // Histogram from contiguous keys.
  for (int idx = tid; idx < M; idx += 1024) {
    u64 key = keys[idx];
    int bi = min(max((int)(key >> KSHIFT) - HBASE, 0), NB - 1);
    atomicAdd(&hist[bi], 1u);
  }
  __syncthreads();

  // T_B: serial suffix walk (cold path).
  if (tid == 0) {
    int acc = 0, tb = 0;
    for (int bi = NB - 1; bi >= 0; bi--) {
      acc += (int)hist[bi];
      if (acc >= KPRE) { tb = bi; break; }
    }
    if (acc > CAPB) tb = min(tb + 1, NB - 1);  // fat-bucket guard
    misc[1] = tb;
    misc[4] = 0;
  }
  __syncthreads();
  int T_B = misc[1];

  // Compact bucket >= T_B into U2 (ballot-aggregated).
  for (int idx0 = 0; idx0 < M; idx0 += 1024) {
    int idx = idx0 + tid;
    bool pred = false;
    u64 key = 0;
    if (idx < M) {
      key = keys[idx];
      int bi = min(max((int)(key >> KSHIFT) - HBASE, 0), NB - 1);
      pred = (bi >= T_B);
    }
    u64 mk = __ballot(pred);
    if (mk) {
      int wbase = 0;
      if (lane == 0) wbase = atomicAdd(&misc[4], __popcll(mk));
      wbase = __shfl(wbase, 0);
      if (pred) {
        int pos = wbase + __popcll(mk & ((1ull << lane) - 1));
        if (pos < CAPB) U2[pos] = key;
      }
    }
  }
  __syncthreads();
  int S = misc[4];
  if (S > CAPB) S = CAPB;
  {  // rank-scatter sort, 2 keys/thread
    int j1 = tid, j2 = tid + 1024;
    u64 k1 = (j1 < S) ? U2[j1] : 0ULL;
    u64 k2 = (j2 < S) ? U2[j2] : 0ULL;
    int r1 = 0, r2 = 0;
    for (int k = 0; k < S; k++) {
      u64 kk = U2[k];
      r1 += (kk > k1);
      r2 += (kk > k2);
    }
    __syncthreads();
    if (j1 < S) SSB[r1] = k1;
    if (j2 < S) SSB[r2] = k2;
  }
  __syncthreads();
  int K = (S < KPRE) ? S : KPRE;  // exact top-2000 (or all if fewer)
  // NMS with per-thread register boxes.
  int j1 = tid, j2 = tid + 1024;
  bool kp1 = (j1 < K), kp2 = (j2 < K);
  float4 bb1 = kp1 ? decode_one(SSB[j1], reg, props, b, h, w, offscale)
                   : make_float4(0, 0, 0, 0);
  float4 bb2 = kp2 ? decode_one(SSB[j2], reg, props, b, h, w, offscale)
                   : make_float4(0, 0, 0, 0);
  int nk = 0;
  if (K > 0) {
    int i = 0;
    for (;;) {
      if (tid == 0) { outl[nk] = i; misc[5] = K; }
      nk++;
      if (nk >= MAXDET) break;
      __syncthreads();
      float4 tb = decode_one(SSB[i], reg, props, b, h, w, offscale);
      float ai = (tb.z - tb.x) * (tb.w - tb.y);
      int ln = K;
      if (kp1 && j1 > i) {
        float aj = (bb1.z - bb1.x) * (bb1.w - bb1.y);
        float iw = fmaxf(fminf(tb.z, bb1.z) - fmaxf(tb.x, bb1.x), 0.0f);
        float ih = fmaxf(fminf(tb.w, bb1.w) - fmaxf(tb.y, bb1.y), 0.0f);
        float inter = iw * ih;
        float iou = inter / (ai + aj - inter + 1e-6f);
        if (iou > 0.5f) kp1 = false;
        else ln = min(ln, j1);
      }
      if (kp2 && j2 > i) {
        float aj = (bb2.z - bb2.x) * (bb2.w - bb2.y);
        float iw = fmaxf(fminf(tb.z, bb2.z) - fmaxf(tb.x, bb2.x), 0.0f);
        float ih = fmaxf(fminf(tb.w, bb2.w) - fmaxf(tb.y, bb2.y), 0.0f);
        float inter = iw * ih;
        float iou = inter / (ai + aj - inter + 1e-6f);
        if (iou > 0.5f) kp2 = false;
        else ln = min(ln, j2);
      }
#pragma unroll
      for (int off = 32; off; off >>= 1) ln = min(ln, __shfl_xor(ln, off));
      if ((tid & 63) == 0 && ln < K) atomicMin(&misc[5], ln);
      __syncthreads();
      int ni = misc[5];
      __syncthreads();
      if (ni >= K) break;
      i = ni;
    }
  }
  if (tid == 0) misc[6] = nk;
  __syncthreads();
  int nkept = misc[6];

  float* oBox = out;
  float* oSc = out + B_ * MAXDET * 4;
  float* oLb = out + B_ * MAXDET * 5;
  for (int k2 = tid; k2 < MAXDET; k2 += 1024) {
    float4 bb = make_float4(0.0f, 0.0f, 0.0f, 0.0f);
    float sv = 0.0f, lv = -1.0f;
    if (k2 < nkept) {
      int idx = outl[k2];
      u64 kk = SSB[idx];
      sv = __uint_as_float((u32)(kk >> 32));
      unsigned fi = 0xFFFFFFFFu - (u32)kk;
      int c = (int)(fi % (unsigned)C_);
      float off = (float)c * offscale;
      float4 ob = decode_one(kk, reg, props, b, h, w, offscale);
      bb = make_float4(ob.x - off, ob.y - off, ob.z - off, ob.w - off);
      lv = (float)c;
    }
    oBox[(b * MAXDET + k2) * 4 + 0] = bb.x;
    oBox[(b * MAXDET + k2) * 4 + 1] = bb.y;
    oBox[(b * MAXDET + k2) * 4 + 2] = bb.z;
    oBox[(b * MAXDET + k2) * 4 + 3] = bb.w;
    oSc[b * MAXDET + k2] = sv;
    oLb[b * MAXDET + k2] = lv;
  }
}

extern "C" void kernel_launch(void* const* d_in, const int* in_sizes, int n_in,
                              void* d_out, int out_size, void* d_ws, size_t ws_size,
                              hipStream_t stream) {
  const float* cls = (const float*)d_in[0];    // [B,N,81] f32
  const float* reg = (const float*)d_in[1];    // [B,N,320] f32
  const float* props = (const float*)d_in[2];  // [B,N,4] f32
  const int* hw = (const int*)d_in[3];         // [B,2] i32
  float* out = (float*)d_out;                  // 2400 f32

  u32* gcur = (u32*)((char*)d_ws + WS_GCUR);
  u32* ghist = (u32*)((char*)d_ws + WS_GHIST);
  int* gflag = (int*)((char*)d_ws + WS_GFLAG);
  u64* gkeys = (u64*)((char*)d_ws + WS_GKEYS);
  float4* gbox = (float4*)((char*)d_ws + WS_GBOX);

  hipMemsetAsync(d_ws, 0, WS_ZEND, stream);
  cand_kernel<<<B_ * BPI, 1024, 0, stream>>>(cls, reg, props, hw,
                                             gkeys, gbox, gcur, ghist);
  nms_kernel<<<B_, 1024, 0, stream>>>(hw, gkeys, gbox, gcur, ghist, gflag, out);
  nmsB_kernel<<<B_, 1024, 0, stream>>>(reg, props, hw, gkeys, gcur, gflag, out);
}